// Round 2
// baseline (163.658 us; speedup 1.0000x reference)
//
#include <hip/hip_runtime.h>
#include <math.h>

#define V    4096
#define NB   8
#define TPB  256
#define Q    4            // queries per thread
#define QPB  (TPB * Q)    // 1024 queries per block
#define QCH  (V / QPB)    // 4 query chunks

// Phase 1: block = (rchunk, qchunk, dirn). Stages its ref chunk into LDS as
// packed float4 (x,y,z,|r|^2); each thread owns Q=4 queries and scans the
// chunk via broadcast ds_read_b128 (1 LDS inst per 20 VALU ops).
// Writes clamp(q2 + min_chunk) to partial[dirn][rchunk][q] — one writer per
// cell, no atomics. max(.,0) and min/max commute, so per-chunk clamp is safe.
__global__ __launch_bounds__(TPB) void hausdorff_partial(
    const float* __restrict__ x, const float* __restrict__ y,
    float* __restrict__ partial, int nrch)
{
    __shared__ float  sraw[3 * 1024];   // 12 KB staging (max RCHUNK=1024)
    __shared__ float4 sref[1024];       // 16 KB packed (x,y,z,r2)

    const int rchunk_sz = V / nrch;
    const int rc   = blockIdx.x;
    const int qch  = blockIdx.y;
    const int dirn = blockIdx.z;        // 0..15: n = dirn&7, dir = dirn>>3
    const int n    = dirn & 7;
    const int dir  = dirn >> 3;
    const int t    = threadIdx.x;

    const float* qb = (dir == 0 ? x : y) + (size_t)n * (3 * V);
    const float* rb = (dir == 0 ? y : x) + (size_t)n * (3 * V) + (size_t)rc * (3 * rchunk_sz);

    // Stage: coalesced scalar loads of 3*rchunk_sz floats.
    for (int i = t; i < 3 * rchunk_sz; i += TPB)
        sraw[i] = rb[i];
    __syncthreads();
    // Pack: stride-3 reads, gcd(3,32)=1 -> conflict-free.
    for (int p = t; p < rchunk_sz; p += TPB) {
        float rx = sraw[3 * p], ry = sraw[3 * p + 1], rz = sraw[3 * p + 2];
        sref[p] = make_float4(rx, ry, rz, rx * rx + ry * ry + rz * rz);
    }

    // Load Q query points (stride TPB -> coalesced partial stores later).
    float qx[Q], qy[Q], qz[Q], q2[Q], m[Q];
    #pragma unroll
    for (int k = 0; k < Q; ++k) {
        int qi = qch * QPB + k * TPB + t;
        qx[k] = qb[3 * qi]; qy[k] = qb[3 * qi + 1]; qz[k] = qb[3 * qi + 2];
        q2[k] = qx[k] * qx[k] + qy[k] * qy[k] + qz[k] * qz[k];
        m[k]  = 3.0e38f;
    }
    __syncthreads();

    // Main loop: per ref point, 1 broadcast ds_read_b128 + 20 VALU.
    #pragma unroll 4
    for (int j = 0; j < rchunk_sz; ++j) {
        float4 p = sref[j];
        #pragma unroll
        for (int k = 0; k < Q; ++k) {
            float d = fmaf(qx[k], p.x, fmaf(qy[k], p.y, qz[k] * p.z));
            m[k] = fminf(m[k], fmaf(-2.0f, d, p.w));
        }
    }

    // partial[dirn][rc][qi], qi contiguous across lanes -> coalesced.
    float* out = partial + ((size_t)dirn * nrch + rc) * V + qch * QPB;
    #pragma unroll
    for (int k = 0; k < Q; ++k)
        out[k * TPB + t] = fmaxf(q2[k] + m[k], 0.0f);
}

// Phase 2: one block per batch n. min over rchunks, max over (dir, q),
// sqrt, atomicAdd(mean contribution).
__global__ __launch_bounds__(TPB) void hausdorff_reduce(
    const float* __restrict__ partial, float* __restrict__ out, int nrch)
{
    const int n = blockIdx.x;
    const int t = threadIdx.x;
    float v = 0.0f;
    for (int dir = 0; dir < 2; ++dir) {
        const float* base = partial + (size_t)(dir * NB + n) * nrch * V;
        for (int q = t; q < V; q += TPB) {
            float mn = 3.0e38f;
            for (int rc = 0; rc < nrch; ++rc)
                mn = fminf(mn, base[(size_t)rc * V + q]);
            v = fmaxf(v, mn);
        }
    }
    // wave reduce
    #pragma unroll
    for (int off = 32; off > 0; off >>= 1)
        v = fmaxf(v, __shfl_xor(v, off));
    __shared__ float sv[TPB / 64];
    if ((t & 63) == 0) sv[t >> 6] = v;
    __syncthreads();
    if (t == 0) {
        float b = sv[0];
        #pragma unroll
        for (int w = 1; w < TPB / 64; ++w) b = fmaxf(b, sv[w]);
        atomicAdd(out, sqrtf(b) * (1.0f / NB));
    }
}

extern "C" void kernel_launch(void* const* d_in, const int* in_sizes, int n_in,
                              void* d_out, int out_size, void* d_ws, size_t ws_size,
                              hipStream_t stream)
{
    const float* x = (const float*)d_in[0];
    const float* y = (const float*)d_in[1];
    float* partial = (float*)d_ws;

    // Pick rchunk count that fits the workspace: 16 (4 MB) preferred.
    int nrch = 16;
    while (nrch > 4 && (size_t)(16 * nrch * V) * sizeof(float) > ws_size)
        nrch >>= 1;

    hipMemsetAsync(d_out, 0, sizeof(float), stream);  // accumulator for mean

    dim3 grid(nrch, QCH, 16);
    hausdorff_partial<<<grid, TPB, 0, stream>>>(x, y, partial, nrch);
    hausdorff_reduce<<<NB, TPB, 0, stream>>>(partial, (float*)d_out, nrch);
}

// Round 3
// 79.640 us; speedup vs baseline: 2.0550x; 2.0550x over previous
//
#include <hip/hip_runtime.h>
#include <math.h>

#define V     4096
#define NB    8
#define TPB   256
#define NRCH  32              // ref chunks
#define RCH   (V / NRCH)      // 128 refs per chunk
#define Q     8               // queries per thread
#define QPB   (TPB * Q)       // 2048 queries per block
#define QCH   (V / QPB)       // 2 query chunks

// Phase 1: block = (rchunk, qchunk, dirn). Stages its 128-point ref chunk in
// LDS packed as (-2x,-2y,-2z,|r|^2) so each (query,ref) pair costs exactly
// 3 fmaf + 1 fminf. Each thread owns Q=8 queries; one broadcast ds_read_b128
// per ref point is amortized over 32 VALU insts. Epilogue: clamp(q2+m, 0)
// and atomicMin (uint bits, order-independent) into cells[dirn][q].
// Grid = 32*2*16 = 1024 blocks -> 4 waves/SIMD for latency hiding.
__global__ __launch_bounds__(TPB) void hausdorff_min(
    const float* __restrict__ x, const float* __restrict__ y,
    unsigned int* __restrict__ cells)
{
    __shared__ float  sraw[3 * RCH];   // 1.5 KB raw staging
    __shared__ float4 sref[RCH];       // 2 KB packed (-2x,-2y,-2z,r2)

    const int rc   = blockIdx.x;
    const int qch  = blockIdx.y;
    const int dirn = blockIdx.z;       // n = dirn&7, dir = dirn>>3
    const int n    = dirn & (NB - 1);
    const int dir  = dirn >> 3;
    const int t    = threadIdx.x;

    const float* qb = (dir ? y : x) + (size_t)n * (3 * V);
    const float* rb = (dir ? x : y) + (size_t)n * (3 * V) + rc * (3 * RCH);

    // Stage 384 floats (2 partially-active rounds), coalesced.
    for (int i = t; i < 3 * RCH; i += TPB)
        sraw[i] = rb[i];

    // Query points (global loads, independent of LDS staging).
    float qx[Q], qy[Q], qz[Q], q2[Q], m[Q];
    #pragma unroll
    for (int k = 0; k < Q; ++k) {
        int qi = qch * QPB + k * TPB + t;
        qx[k] = qb[3 * qi]; qy[k] = qb[3 * qi + 1]; qz[k] = qb[3 * qi + 2];
        q2[k] = qx[k] * qx[k] + qy[k] * qy[k] + qz[k] * qz[k];
        m[k]  = 3.0e38f;
    }
    __syncthreads();

    // Pack pass: stride-3 reads, gcd(3,32)=1 -> conflict-free.
    if (t < RCH) {
        float rx = sraw[3 * t], ry = sraw[3 * t + 1], rz = sraw[3 * t + 2];
        sref[t] = make_float4(-2.0f * rx, -2.0f * ry, -2.0f * rz,
                              rx * rx + ry * ry + rz * rz);
    }
    __syncthreads();

    // Main loop: 128 iters x (1 broadcast ds_read_b128 + 32 VALU).
    #pragma unroll 8
    for (int j = 0; j < RCH; ++j) {
        float4 p = sref[j];
        #pragma unroll
        for (int k = 0; k < Q; ++k) {
            float d = fmaf(qx[k], p.x, fmaf(qy[k], p.y, fmaf(qz[k], p.z, p.w)));
            m[k] = fminf(m[k], d);
        }
    }

    // clamp commutes with min over chunks; uint-bit atomicMin is exact & ordered
    // for nonneg floats. Fire-and-forget -> overlaps other blocks' compute.
    unsigned int* cell = cells + (size_t)dirn * V + qch * QPB + t;
    #pragma unroll
    for (int k = 0; k < Q; ++k)
        atomicMin(cell + k * TPB, __float_as_uint(fmaxf(q2[k] + m[k], 0.0f)));
}

// Phase 2: block n reads its two directed rows (2*4096 cells, uint4 loads),
// block-wide max, sqrt, atomicAdd of the mean contribution.
__global__ __launch_bounds__(1024) void hausdorff_final(
    const unsigned int* __restrict__ cells, float* __restrict__ out)
{
    const int n = blockIdx.x;
    const int t = threadIdx.x;
    const uint4* c0 = (const uint4*)(cells + (size_t)n * V);
    const uint4* c1 = (const uint4*)(cells + (size_t)(NB + n) * V);
    uint4 a = c0[t], b = c1[t];   // V/4 = 1024 = blockDim exactly
    float v = fmaxf(fmaxf(fmaxf(__uint_as_float(a.x), __uint_as_float(a.y)),
                          fmaxf(__uint_as_float(a.z), __uint_as_float(a.w))),
                    fmaxf(fmaxf(__uint_as_float(b.x), __uint_as_float(b.y)),
                          fmaxf(__uint_as_float(b.z), __uint_as_float(b.w))));
    #pragma unroll
    for (int off = 32; off > 0; off >>= 1)
        v = fmaxf(v, __shfl_xor(v, off));
    __shared__ float sv[16];
    if ((t & 63) == 0) sv[t >> 6] = v;
    __syncthreads();
    if (t < 64) {
        float w = (t < 16) ? sv[t] : 0.0f;
        #pragma unroll
        for (int off = 8; off > 0; off >>= 1)
            w = fmaxf(w, __shfl_xor(w, off));
        if (t == 0)
            atomicAdd(out, sqrtf(w) * (1.0f / NB));
    }
}

extern "C" void kernel_launch(void* const* d_in, const int* in_sizes, int n_in,
                              void* d_out, int out_size, void* d_ws, size_t ws_size,
                              hipStream_t stream)
{
    const float* x = (const float*)d_in[0];
    const float* y = (const float*)d_in[1];
    unsigned int* cells = (unsigned int*)d_ws;   // 16 * 4096 * 4 B = 256 KB

    // out accumulates the mean; cells init to +huge (0x7f7f7f7f = 3.39e38f,
    // uint-order == float-order for nonneg).
    hipMemsetAsync(d_out, 0, sizeof(float), stream);
    hipMemsetAsync(cells, 0x7F, (size_t)2 * NB * V * sizeof(unsigned int), stream);

    hausdorff_min<<<dim3(NRCH, QCH, 2 * NB), TPB, 0, stream>>>(x, y, cells);
    hausdorff_final<<<NB, 1024, 0, stream>>>(cells, (float*)d_out);
}